// Round 9
// baseline (328.388 us; speedup 1.0000x reference)
//
#include <hip/hip_runtime.h>
#include <hip/hip_bf16.h>
#include <math.h>

#define D_MODEL 1024
#define NUM_HEADS 16
#define DEPTH 64
#define BATCH 2
#define SEQ 2048
#define N_TOK (BATCH * SEQ)   // 4096

typedef short bf16x8 __attribute__((ext_vector_type(8)));
typedef float f32x4  __attribute__((ext_vector_type(4)));
typedef unsigned short u16x8 __attribute__((ext_vector_type(8)));
typedef unsigned short u16x4 __attribute__((ext_vector_type(4)));

__device__ __forceinline__ unsigned short f2b(float x) {
    return __builtin_bit_cast(unsigned short, __float2bfloat16(x));
}
__device__ __forceinline__ float b2f(unsigned short h) {
    return __builtin_bit_cast(float, (unsigned int)h << 16);
}

// ---------------------------------------------------------------------------
// Elementwise fp32 -> (bf16 hi, bf16 lo) split (Fast2Sum residual).
// ---------------------------------------------------------------------------
__global__ __launch_bounds__(256) void split_bf16x2(
    const float* __restrict__ src,
    unsigned short* __restrict__ hi,
    unsigned short* __restrict__ lo,
    int n8)
{
    const int i = blockIdx.x * 256 + threadIdx.x;
    if (i >= n8) return;
    const float4 f0 = ((const float4*)src)[2 * i];
    const float4 f1 = ((const float4*)src)[2 * i + 1];
    const float xs[8] = {f0.x, f0.y, f0.z, f0.w, f1.x, f1.y, f1.z, f1.w};
    u16x8 h8, l8;
    #pragma unroll
    for (int e = 0; e < 8; ++e) {
        const unsigned short h = f2b(xs[e]);
        h8[e] = h;
        l8[e] = f2b(xs[e] - b2f(h));
    }
    *(u16x8*)&hi[(size_t)i * 8] = h8;
    *(u16x8*)&lo[(size_t)i * 8] = l8;
}

// Same split for the 4 weight matrices in ONE dispatch.
__global__ __launch_bounds__(256) void split4_bf16x2(
    const float* __restrict__ s0, const float* __restrict__ s1,
    const float* __restrict__ s2, const float* __restrict__ s3,
    unsigned short* __restrict__ h0, unsigned short* __restrict__ l0,
    unsigned short* __restrict__ h1, unsigned short* __restrict__ l1,
    unsigned short* __restrict__ h2, unsigned short* __restrict__ l2,
    unsigned short* __restrict__ h3, unsigned short* __restrict__ l3,
    int n8)
{
    const float* src; unsigned short* hi; unsigned short* lo;
    switch (blockIdx.y) {
        case 0:  src = s0; hi = h0; lo = l0; break;
        case 1:  src = s1; hi = h1; lo = l1; break;
        case 2:  src = s2; hi = h2; lo = l2; break;
        default: src = s3; hi = h3; lo = l3; break;
    }
    const int i = blockIdx.x * 256 + threadIdx.x;
    if (i >= n8) return;
    const float4 f0 = ((const float4*)src)[2 * i];
    const float4 f1 = ((const float4*)src)[2 * i + 1];
    const float xs[8] = {f0.x, f0.y, f0.z, f0.w, f1.x, f1.y, f1.z, f1.w};
    u16x8 h8, l8;
    #pragma unroll
    for (int e = 0; e < 8; ++e) {
        const unsigned short h = f2b(xs[e]);
        h8[e] = h;
        l8[e] = f2b(xs[e] - b2f(h));
    }
    *(u16x8*)&hi[(size_t)i * 8] = h8;
    *(u16x8*)&lo[(size_t)i * 8] = l8;
}

// ---------------------------------------------------------------------------
// bf16x3 split GEMM v5:  Y[i][j] = (sum_k X[i][k]*W[j][k] + bias[j]) * scale
// R9: tile 64x64, BK=64, 256 thr (4 waves, each a 32x32 quadrant: 2x2 grid
// of 16x16x32 MFMAs, 3 per tile). Grid (16 j, 64 i) = 1024 blocks =
// 4 blocks/CU (LDS 32 KB -> 128 KB/CU), 4 waves/SIMD. R8 post-mortem:
// grid 256 = 1 block/CU could never overlap the per-slab barrier drains;
// 4 co-resident blocks give m114-style cross-block MFMA/stage overlap.
// Per-output K-chain (slab -> ks -> hh,hl,lh) identical to R7/R8 ->
// bit-identical results.
// Per-XCD L2: round-robin dispatch puts j-blocks {k, k+8} on XCD k ->
// B working set ~0.5 MB/XCD (resident); A streams through L2/L3.
// mode 0: fp32 flat [i][1024]; mode 1: bf16 [bh][s][64]; mode 2: bf16 [bh][d][s].
// ---------------------------------------------------------------------------
__global__ __launch_bounds__(256, 4) void gemm_bf16x3(
    const unsigned short* __restrict__ Ahi,  // [4096][1024] bf16
    const unsigned short* __restrict__ Alo,
    const unsigned short* __restrict__ Bhi,  // [1024][1024] bf16
    const unsigned short* __restrict__ Blo,
    const float* __restrict__ bias,          // [1024]
    void* __restrict__ Yv,
    float scale,
    int mode)
{
    __shared__ unsigned short sAh[64][64];
    __shared__ unsigned short sAl[64][64];
    __shared__ unsigned short sBh[64][64];
    __shared__ unsigned short sBl[64][64];

    const int tid  = threadIdx.x;
    const int wave = tid >> 6;
    const int lane = tid & 63;
    const int quad = lane >> 4;
    const int l16  = lane & 15;
    const int wm   = wave >> 1;          // 0..1 -> 32-row strip
    const int wn   = wave & 1;           // 0..1 -> 32-col strip

    const int j0 = blockIdx.x * 64;
    const int i0 = blockIdx.y * 64;

    // staging: 4 passes x 32 rows: p<2 -> A rows p*32+r32, p>=2 -> B rows.
    const int sc  = tid & 7;             // physical 16B chunk
    const int r32 = tid >> 3;            // 0..31

    u16x8 preH[4], preL[4];

    #pragma unroll
    for (int p = 0; p < 4; ++p) {
        const bool isA = p < 2;
        const int row = (p & 1) * 32 + r32;
        const unsigned short* srcH = isA ? Ahi : Bhi;
        const unsigned short* srcL = isA ? Alo : Blo;
        const int grow = (isA ? i0 : j0) + row;
        const int cg = (sc ^ (row & 7)) * 8;
        const size_t go = (size_t)grow * 1024 + cg;
        preH[p] = *(const u16x8*)&srcH[go];
        preL[p] = *(const u16x8*)&srcL[go];
    }

    f32x4 acc[2][2] = {};                // [mt][nt]

    for (int s = 0; s < 16; ++s) {
        __syncthreads();  // prior slab's frag reads complete

        // ---- drain prefetch regs into LDS (swizzled) ----
        #pragma unroll
        for (int p = 0; p < 4; ++p) {
            const bool isA = p < 2;
            const int row = (p & 1) * 32 + r32;
            unsigned short (*dh)[64] = isA ? sAh : sBh;
            unsigned short (*dl)[64] = isA ? sAl : sBl;
            *(u16x8*)&dh[row][sc * 8] = preH[p];
            *(u16x8*)&dl[row][sc * 8] = preL[p];
        }
        __syncthreads();

        // ---- issue next slab's loads; they fly during compute ----
        if (s + 1 < 16) {
            const int k0 = (s + 1) * 64;
            #pragma unroll
            for (int p = 0; p < 4; ++p) {
                const bool isA = p < 2;
                const int row = (p & 1) * 32 + r32;
                const unsigned short* srcH = isA ? Ahi : Bhi;
                const unsigned short* srcL = isA ? Alo : Blo;
                const int grow = (isA ? i0 : j0) + row;
                const int cg = (sc ^ (row & 7)) * 8;
                const size_t go = (size_t)grow * 1024 + k0 + cg;
                preH[p] = *(const u16x8*)&srcH[go];
                preL[p] = *(const u16x8*)&srcL[go];
            }
        }

        // ---- compute: 2 k-steps x (2 mt x 2 nt) tiles x 3 MFMAs ----
        #pragma unroll
        for (int ks = 0; ks < 2; ++ks) {
            bf16x8 ah[2], al[2], bh[2], bl[2];
            #pragma unroll
            for (int mt = 0; mt < 2; ++mt) {
                const int row = wm * 32 + mt * 16 + l16;
                const int c = (((ks * 4 + quad) ^ (row & 7))) * 8;
                ah[mt] = *(const bf16x8*)&sAh[row][c];
                al[mt] = *(const bf16x8*)&sAl[row][c];
            }
            #pragma unroll
            for (int nt = 0; nt < 2; ++nt) {
                const int row = wn * 32 + nt * 16 + l16;
                const int c = (((ks * 4 + quad) ^ (row & 7))) * 8;
                bh[nt] = *(const bf16x8*)&sBh[row][c];
                bl[nt] = *(const bf16x8*)&sBl[row][c];
            }
            #pragma unroll
            for (int mt = 0; mt < 2; ++mt)
                #pragma unroll
                for (int nt = 0; nt < 2; ++nt) {
                    acc[mt][nt] = __builtin_amdgcn_mfma_f32_16x16x32_bf16(ah[mt], bh[nt], acc[mt][nt], 0, 0, 0);
                    acc[mt][nt] = __builtin_amdgcn_mfma_f32_16x16x32_bf16(ah[mt], bl[nt], acc[mt][nt], 0, 0, 0);
                    acc[mt][nt] = __builtin_amdgcn_mfma_f32_16x16x32_bf16(al[mt], bh[nt], acc[mt][nt], 0, 0, 0);
                }
        }
    }

    // ---- epilogue ----
    float bv[2];
    #pragma unroll
    for (int nt = 0; nt < 2; ++nt)
        bv[nt] = bias[j0 + wn * 32 + nt * 16 + l16];

    #pragma unroll
    for (int mt = 0; mt < 2; ++mt) {
        const int ibase = i0 + wm * 32 + mt * 16 + quad * 4;  // + r
        #pragma unroll
        for (int nt = 0; nt < 2; ++nt) {
            const int j = j0 + wn * 32 + nt * 16 + l16;
            if (mode == 0) {
                float* Y = (float*)Yv;
                #pragma unroll
                for (int r = 0; r < 4; ++r)
                    Y[(size_t)(ibase + r) * 1024 + j] = (acc[mt][nt][r] + bv[nt]) * scale;
            } else if (mode == 1) {
                __hip_bfloat16* Y = (__hip_bfloat16*)Yv;
                const int h = j >> 6, d = j & 63;
                #pragma unroll
                for (int r = 0; r < 4; ++r) {
                    const int i = ibase + r;
                    const int b = i >> 11, ss = i & (SEQ - 1);
                    Y[(((size_t)(b * NUM_HEADS + h) * SEQ) + ss) * DEPTH + d] =
                        __float2bfloat16((acc[mt][nt][r] + bv[nt]) * scale);
                }
            } else {
                unsigned short* Y = (unsigned short*)Yv;
                const int h = j >> 6, d = j & 63;
                const int b = ibase >> 11;    // 64-row tile stays in one batch
                u16x4 pack;
                #pragma unroll
                for (int r = 0; r < 4; ++r)
                    pack[r] = f2b((acc[mt][nt][r] + bv[nt]) * scale);
                *(u16x4*)&Y[(((size_t)(b * NUM_HEADS + h) * DEPTH) + d) * SEQ
                            + (ibase & (SEQ - 1))] = pack;
            }
        }
    }
}

// ---------------------------------------------------------------------------
// bf16 MFMA flash attention v3 (unchanged from R8 — 76.6 us).
// R3 post-mortem: all three __syncthreads() are load-bearing; the P-write ->
// P-read barrier guards a cross-lane LDS round-trip. Do not remove.
// ---------------------------------------------------------------------------
__global__ __launch_bounds__(256) void flash_attn_mfma(
    const __hip_bfloat16* __restrict__ Qg,  // [BH][S][DEPTH], pre-scaled by 1/8
    const __hip_bfloat16* __restrict__ Kg,  // [BH][S][DEPTH]
    const __hip_bfloat16* __restrict__ Vg,  // [BH][DEPTH][S]
    unsigned short* __restrict__ OHi,       // [N_TOK][D_MODEL] bf16 hi
    unsigned short* __restrict__ OLo)       // [N_TOK][D_MODEL] bf16 lo
{
    __shared__ unsigned short Ks[64][72];
    __shared__ unsigned short Vt[64][72];
    __shared__ unsigned short Ps[4][16][68];

    const int tid  = threadIdx.x;
    const int wave = tid >> 6;
    const int lane = tid & 63;
    const int quad = lane >> 4;
    const int l16  = lane & 15;

    const int bh = blockIdx.x >> 5;
    const int q0 = (blockIdx.x & 31) * 64;

    const unsigned short* Qu = (const unsigned short*)Qg + (size_t)bh * SEQ * DEPTH;
    const unsigned short* Ku = (const unsigned short*)Kg + (size_t)bh * SEQ * DEPTH;
    const unsigned short* Vu = (const unsigned short*)Vg + (size_t)bh * DEPTH * SEQ;

    const int qrow = q0 + wave * 16 + l16;
    bf16x8 qf[2];
    qf[0] = *(const bf16x8*)&Qu[(size_t)qrow * DEPTH + quad * 8];
    qf[1] = *(const bf16x8*)&Qu[(size_t)qrow * DEPTH + 32 + quad * 8];

    bf16x8 ones;
    #pragma unroll
    for (int e = 0; e < 8; ++e) ones[e] = (short)0x3F80;  // bf16 1.0

    f32x4 o_acc[4] = {};
    f32x4 l_acc = {0.f, 0.f, 0.f, 0.f};

    const int srow = tid >> 3;          // 0..31
    const int sc8  = (tid & 7) * 8;
    u16x8 kpre[2], vpre[2];
    #pragma unroll
    for (int it = 0; it < 2; ++it) {
        const int row = it * 32 + srow;
        kpre[it] = *(const u16x8*)&Ku[(size_t)row * DEPTH + sc8];
        vpre[it] = *(const u16x8*)&Vu[(size_t)row * SEQ + sc8];
    }

    for (int t = 0; t < 32; ++t) {
        __syncthreads();  // prior tile's Ks/Vt reads complete

        #pragma unroll
        for (int it = 0; it < 2; ++it) {
            const int row = it * 32 + srow;
            *(u16x8*)&Ks[row][sc8] = kpre[it];
            *(u16x8*)&Vt[row][sc8] = vpre[it];
        }
        __syncthreads();

        if (t + 1 < 32) {
            const int k0 = (t + 1) * 64;
            #pragma unroll
            for (int it = 0; it < 2; ++it) {
                const int row = it * 32 + srow;
                kpre[it] = *(const u16x8*)&Ku[(size_t)(k0 + row) * DEPTH + sc8];
                vpre[it] = *(const u16x8*)&Vu[(size_t)row * SEQ + k0 + sc8];
            }
        }

        // ---- S = Q K^T (Q pre-scaled by 1/8) ----
        f32x4 s[4];
        #pragma unroll
        for (int nt = 0; nt < 4; ++nt) {
            s[nt] = f32x4{0.f, 0.f, 0.f, 0.f};
            bf16x8 kf0 = *(const bf16x8*)&Ks[nt * 16 + l16][quad * 8];
            s[nt] = __builtin_amdgcn_mfma_f32_16x16x32_bf16(qf[0], kf0, s[nt], 0, 0, 0);
            bf16x8 kf1 = *(const bf16x8*)&Ks[nt * 16 + l16][32 + quad * 8];
            s[nt] = __builtin_amdgcn_mfma_f32_16x16x32_bf16(qf[1], kf1, s[nt], 0, 0, 0);
        }

        // ---- p = exp(s) -> bf16 P strip (no max subtraction; see R7) ----
        #pragma unroll
        for (int nt = 0; nt < 4; ++nt)
            #pragma unroll
            for (int r = 0; r < 4; ++r)
                Ps[wave][quad * 4 + r][nt * 16 + l16] = f2b(__expf(s[nt][r]));

        __syncthreads();  // R3 fix — REQUIRED (cross-lane P round-trip)

        // ---- reread P as A-fragments (2 x b64 per frag; pitch-68 rows) ----
        bf16x8 pf[2];
        {
            u16x4 a0 = *(const u16x4*)&Ps[wave][l16][quad * 8];
            u16x4 a1 = *(const u16x4*)&Ps[wave][l16][quad * 8 + 4];
            u16x4 b0 = *(const u16x4*)&Ps[wave][l16][32 + quad * 8];
            u16x4 b1 = *(const u16x4*)&Ps[wave][l16][32 + quad * 8 + 4];
            #pragma unroll
            for (int e = 0; e < 4; ++e) {
                pf[0][e] = (short)a0[e]; pf[0][4 + e] = (short)a1[e];
                pf[1][e] = (short)b0[e]; pf[1][4 + e] = (short)b1[e];
            }
        }

        // ---- O += P V ; row sums += P @ ones ----
        #pragma unroll
        for (int nt = 0; nt < 4; ++nt) {
            bf16x8 vf0 = *(const bf16x8*)&Vt[nt * 16 + l16][quad * 8];
            o_acc[nt] = __builtin_amdgcn_mfma_f32_16x16x32_bf16(pf[0], vf0, o_acc[nt], 0, 0, 0);
            bf16x8 vf1 = *(const bf16x8*)&Vt[nt * 16 + l16][32 + quad * 8];
            o_acc[nt] = __builtin_amdgcn_mfma_f32_16x16x32_bf16(pf[1], vf1, o_acc[nt], 0, 0, 0);
        }
        l_acc = __builtin_amdgcn_mfma_f32_16x16x32_bf16(pf[0], ones, l_acc, 0, 0, 0);
        l_acc = __builtin_amdgcn_mfma_f32_16x16x32_bf16(pf[1], ones, l_acc, 0, 0, 0);
    }

    // ---- epilogue: normalize, split-store hi/lo ----
    const int b = bh / NUM_HEADS;
    const int h = bh % NUM_HEADS;
    #pragma unroll
    for (int r = 0; r < 4; ++r) {
        const float inv = 1.f / l_acc[r];
        const int row = q0 + wave * 16 + quad * 4 + r;
        #pragma unroll
        for (int nt = 0; nt < 4; ++nt) {
            const float o = o_acc[nt][r] * inv;
            const size_t idx = ((size_t)(b * SEQ + row)) * D_MODEL + h * DEPTH + nt * 16 + l16;
            const unsigned short hbits = f2b(o);
            OHi[idx] = hbits;
            OLo[idx] = f2b(o - b2f(hbits));
        }
    }
}

// ---------------------------------------------------------------------------
extern "C" void kernel_launch(void* const* d_in, const int* in_sizes, int n_in,
                              void* d_out, int out_size, void* d_ws, size_t ws_size,
                              hipStream_t stream) {
    const float* q  = (const float*)d_in[0];
    const float* k  = (const float*)d_in[1];
    const float* v  = (const float*)d_in[2];
    const float* wq = (const float*)d_in[3];
    const float* bq = (const float*)d_in[4];
    const float* wk = (const float*)d_in[5];
    const float* bk = (const float*)d_in[6];
    const float* wv = (const float*)d_in[7];
    const float* bv = (const float*)d_in[8];
    const float* wo = (const float*)d_in[9];
    const float* bo = (const float*)d_in[10];
    float* out = (float*)d_out;

    // Workspace layout (56 MB; Abuf recycled q -> k -> v -> Ao):
    //  [0,  8 MB)  Abuf_hi   [4096][1024] bf16
    //  [8, 16 MB)  Abuf_lo
    //  [16,32 MB)  weight splits hi/lo (2 MB each)
    //  [32,40 MB)  Qh [bh][s][64] bf16 (pre-scaled by 1/8)
    //  [40,48 MB)  Kh [bh][s][64] bf16
    //  [48,56 MB)  Vh [bh][64][s] bf16
    char* ws = (char*)d_ws;
    const size_t MB = 1024 * 1024;
    unsigned short* Ah  = (unsigned short*)(ws);
    unsigned short* Al  = (unsigned short*)(ws + 8 * MB);
    unsigned short* WqH = (unsigned short*)(ws + 16 * MB);
    unsigned short* WqL = (unsigned short*)(ws + 18 * MB);
    unsigned short* WkH = (unsigned short*)(ws + 20 * MB);
    unsigned short* WkL = (unsigned short*)(ws + 22 * MB);
    unsigned short* WvH = (unsigned short*)(ws + 24 * MB);
    unsigned short* WvL = (unsigned short*)(ws + 26 * MB);
    unsigned short* WoH = (unsigned short*)(ws + 28 * MB);
    unsigned short* WoL = (unsigned short*)(ws + 30 * MB);
    __hip_bfloat16* Qh  = (__hip_bfloat16*)(ws + 32 * MB);
    __hip_bfloat16* Kh  = (__hip_bfloat16*)(ws + 40 * MB);
    __hip_bfloat16* Vh  = (__hip_bfloat16*)(ws + 48 * MB);

    const int nW8 = D_MODEL * D_MODEL / 8;   // 131072 -> 512 blocks
    const int nA8 = N_TOK * D_MODEL / 8;     // 524288 -> 2048 blocks
    dim3 sb(256);

    split4_bf16x2<<<dim3(nW8 / 256, 4), sb, 0, stream>>>(
        wq, wk, wv, wo, WqH, WqL, WkH, WkL, WvH, WvL, WoH, WoL, nW8);

    dim3 gblk(256);                          // R9: 4 waves/block
    dim3 ggrid(D_MODEL / 64, N_TOK / 64);    // 16 x 64 = 1024 blocks = 4/CU

    // Q projection (scale folds 1/sqrt(64) into Q)
    split_bf16x2<<<dim3(nA8 / 256), sb, 0, stream>>>(q, Ah, Al, nA8);
    gemm_bf16x3<<<ggrid, gblk, 0, stream>>>(Ah, Al, WqH, WqL, bq, Qh, 0.125f, 1);
    // K projection
    split_bf16x2<<<dim3(nA8 / 256), sb, 0, stream>>>(k, Ah, Al, nA8);
    gemm_bf16x3<<<ggrid, gblk, 0, stream>>>(Ah, Al, WkH, WkL, bk, Kh, 1.0f, 1);
    // V projection (transposed head layout)
    split_bf16x2<<<dim3(nA8 / 256), sb, 0, stream>>>(v, Ah, Al, nA8);
    gemm_bf16x3<<<ggrid, gblk, 0, stream>>>(Ah, Al, WvH, WvL, bv, Vh, 1.0f, 2);

    // attention -> Ao (pre-split hi/lo into recycled Abuf)
    dim3 ablk(256);
    dim3 agrid(BATCH * NUM_HEADS * (SEQ / 64));  // 1024 blocks
    flash_attn_mfma<<<agrid, ablk, 0, stream>>>(Qh, Kh, Vh, Ah, Al);

    // output projection
    gemm_bf16x3<<<ggrid, gblk, 0, stream>>>(Ah, Al, WoH, WoL, bo, out, 1.0f, 0);
}

// Round 10
// 278.555 us; speedup vs baseline: 1.1789x; 1.1789x over previous
//
#include <hip/hip_runtime.h>
#include <hip/hip_bf16.h>
#include <math.h>

#define D_MODEL 1024
#define NUM_HEADS 16
#define DEPTH 64
#define BATCH 2
#define SEQ 2048
#define N_TOK (BATCH * SEQ)   // 4096

typedef short bf16x8 __attribute__((ext_vector_type(8)));
typedef _Float16 f16x8 __attribute__((ext_vector_type(8)));
typedef float f32x4  __attribute__((ext_vector_type(4)));
typedef unsigned short u16x8 __attribute__((ext_vector_type(8)));
typedef unsigned short u16x4 __attribute__((ext_vector_type(4)));

__device__ __forceinline__ unsigned short f2b(float x) {
    return __builtin_bit_cast(unsigned short, __float2bfloat16(x));
}
__device__ __forceinline__ float b2f(unsigned short h) {
    return __builtin_bit_cast(float, (unsigned int)h << 16);
}
__device__ __forceinline__ unsigned short f2h(float x) {
    return __builtin_bit_cast(unsigned short, (_Float16)x);
}

// ---------------------------------------------------------------------------
// fp32 -> fp16 convert (for Q/K/V projection inputs; R10).
// ---------------------------------------------------------------------------
__global__ __launch_bounds__(256) void split_f16(
    const float* __restrict__ src,
    unsigned short* __restrict__ dst,
    int n8)
{
    const int i = blockIdx.x * 256 + threadIdx.x;
    if (i >= n8) return;
    const float4 f0 = ((const float4*)src)[2 * i];
    const float4 f1 = ((const float4*)src)[2 * i + 1];
    const float xs[8] = {f0.x, f0.y, f0.z, f0.w, f1.x, f1.y, f1.z, f1.w};
    u16x8 o;
    #pragma unroll
    for (int e = 0; e < 8; ++e) o[e] = f2h(xs[e]);
    *(u16x8*)&dst[(size_t)i * 8] = o;
}

// Weight prep, one dispatch: wq/wk/wv -> fp16; wo -> bf16 hi/lo (Fast2Sum).
__global__ __launch_bounds__(256) void prep_weights(
    const float* __restrict__ s0, const float* __restrict__ s1,
    const float* __restrict__ s2, const float* __restrict__ s3,
    unsigned short* __restrict__ f0, unsigned short* __restrict__ f1,
    unsigned short* __restrict__ f2,
    unsigned short* __restrict__ h3, unsigned short* __restrict__ l3,
    int n8)
{
    const int i = blockIdx.x * 256 + threadIdx.x;
    if (i >= n8) return;
    const int which = blockIdx.y;
    const float* src = (which == 0) ? s0 : (which == 1) ? s1 : (which == 2) ? s2 : s3;
    const float4 a0 = ((const float4*)src)[2 * i];
    const float4 a1 = ((const float4*)src)[2 * i + 1];
    const float xs[8] = {a0.x, a0.y, a0.z, a0.w, a1.x, a1.y, a1.z, a1.w};
    if (which < 3) {
        unsigned short* dst = (which == 0) ? f0 : (which == 1) ? f1 : f2;
        u16x8 o;
        #pragma unroll
        for (int e = 0; e < 8; ++e) o[e] = f2h(xs[e]);
        *(u16x8*)&dst[(size_t)i * 8] = o;
    } else {
        u16x8 h8, l8;
        #pragma unroll
        for (int e = 0; e < 8; ++e) {
            const unsigned short h = f2b(xs[e]);
            h8[e] = h;
            l8[e] = f2b(xs[e] - b2f(h));
        }
        *(u16x8*)&h3[(size_t)i * 8] = h8;
        *(u16x8*)&l3[(size_t)i * 8] = l8;
    }
}

// ---------------------------------------------------------------------------
// fp16 single-MFMA GEMM (R10, Q/K/V projections):
//   Y[i][j] = (sum_k X[i][k]*W[j][k] + bias[j]) * scale
// R9 post-mortem: bf16x3's 3x MFMA work (481 TF effective) was the wall, not
// occupancy/LDS. fp16 inputs (11-bit precision) give error std ~4e-4, masked
// by the bf16 rounding (2.25e-3) applied to Qh/Kh/Vh anyway.
// Tile 64x64, BK=64, 256 thr / 4 waves, wave = 32x32 quadrant (2x2 MFMA
// tiles); grid (16,64) = 1024 blocks = 4 blocks/CU; LDS 16 KB; register
// prefetch of next slab; XOR 16B-chunk swizzle (conflict-free, R5-audited).
// mode 1: bf16 [bh][s][64]; mode 2: bf16 [bh][d][s].
// ---------------------------------------------------------------------------
__global__ __launch_bounds__(256, 4) void gemm_f16(
    const unsigned short* __restrict__ Af,   // fp16 [4096][1024]
    const unsigned short* __restrict__ Bf,   // fp16 [1024][1024]
    const float* __restrict__ bias,
    void* __restrict__ Yv,
    float scale,
    int mode)
{
    __shared__ unsigned short sA[64][64];
    __shared__ unsigned short sB[64][64];

    const int tid  = threadIdx.x;
    const int wave = tid >> 6;
    const int lane = tid & 63;
    const int quad = lane >> 4;
    const int l16  = lane & 15;
    const int wm   = wave >> 1;
    const int wn   = wave & 1;

    const int j0 = blockIdx.x * 64;
    const int i0 = blockIdx.y * 64;

    const int sc  = tid & 7;
    const int r32 = tid >> 3;            // 0..31

    u16x8 pre[4];
    #pragma unroll
    for (int p = 0; p < 4; ++p) {
        const bool isA = p < 2;
        const int row = (p & 1) * 32 + r32;
        const unsigned short* src = isA ? Af : Bf;
        const int grow = (isA ? i0 : j0) + row;
        const int cg = (sc ^ (row & 7)) * 8;
        pre[p] = *(const u16x8*)&src[(size_t)grow * 1024 + cg];
    }

    f32x4 acc[2][2] = {};

    for (int s = 0; s < 16; ++s) {
        __syncthreads();

        #pragma unroll
        for (int p = 0; p < 4; ++p) {
            const bool isA = p < 2;
            const int row = (p & 1) * 32 + r32;
            unsigned short (*dst)[64] = isA ? sA : sB;
            *(u16x8*)&dst[row][sc * 8] = pre[p];
        }
        __syncthreads();

        if (s + 1 < 16) {
            const int k0 = (s + 1) * 64;
            #pragma unroll
            for (int p = 0; p < 4; ++p) {
                const bool isA = p < 2;
                const int row = (p & 1) * 32 + r32;
                const unsigned short* src = isA ? Af : Bf;
                const int grow = (isA ? i0 : j0) + row;
                const int cg = (sc ^ (row & 7)) * 8;
                pre[p] = *(const u16x8*)&src[(size_t)grow * 1024 + k0 + cg];
            }
        }

        #pragma unroll
        for (int ks = 0; ks < 2; ++ks) {
            f16x8 a[2], b[2];
            #pragma unroll
            for (int mt = 0; mt < 2; ++mt) {
                const int row = wm * 32 + mt * 16 + l16;
                const int c = (((ks * 4 + quad) ^ (row & 7))) * 8;
                a[mt] = *(const f16x8*)&sA[row][c];
            }
            #pragma unroll
            for (int nt = 0; nt < 2; ++nt) {
                const int row = wn * 32 + nt * 16 + l16;
                const int c = (((ks * 4 + quad) ^ (row & 7))) * 8;
                b[nt] = *(const f16x8*)&sB[row][c];
            }
            #pragma unroll
            for (int mt = 0; mt < 2; ++mt)
                #pragma unroll
                for (int nt = 0; nt < 2; ++nt)
                    acc[mt][nt] = __builtin_amdgcn_mfma_f32_16x16x32_f16(a[mt], b[nt], acc[mt][nt], 0, 0, 0);
        }
    }

    float bv[2];
    #pragma unroll
    for (int nt = 0; nt < 2; ++nt)
        bv[nt] = bias[j0 + wn * 32 + nt * 16 + l16];

    #pragma unroll
    for (int mt = 0; mt < 2; ++mt) {
        const int ibase = i0 + wm * 32 + mt * 16 + quad * 4;  // + r
        #pragma unroll
        for (int nt = 0; nt < 2; ++nt) {
            const int j = j0 + wn * 32 + nt * 16 + l16;
            const int h = j >> 6, d = j & 63;
            if (mode == 1) {
                __hip_bfloat16* Y = (__hip_bfloat16*)Yv;
                #pragma unroll
                for (int r = 0; r < 4; ++r) {
                    const int i = ibase + r;
                    const int b = i >> 11, ss = i & (SEQ - 1);
                    Y[(((size_t)(b * NUM_HEADS + h) * SEQ) + ss) * DEPTH + d] =
                        __float2bfloat16((acc[mt][nt][r] + bv[nt]) * scale);
                }
            } else {
                unsigned short* Y = (unsigned short*)Yv;
                const int b = ibase >> 11;
                u16x4 pack;
                #pragma unroll
                for (int r = 0; r < 4; ++r)
                    pack[r] = f2b((acc[mt][nt][r] + bv[nt]) * scale);
                *(u16x4*)&Y[(((size_t)(b * NUM_HEADS + h) * DEPTH) + d) * SEQ
                            + (ibase & (SEQ - 1))] = pack;
            }
        }
    }
}

// ---------------------------------------------------------------------------
// bf16x3 split GEMM (R8's best 512-thread version, unchanged — used only for
// the OUTPUT projection, whose error lands unattenuated on d_out).
// ---------------------------------------------------------------------------
__global__ __launch_bounds__(512, 2) void gemm_bf16x3(
    const unsigned short* __restrict__ Ahi,
    const unsigned short* __restrict__ Alo,
    const unsigned short* __restrict__ Bhi,
    const unsigned short* __restrict__ Blo,
    const float* __restrict__ bias,
    float* __restrict__ Y,                   // fp32 flat [i][1024]
    float scale)
{
    __shared__ unsigned short sAh[128][64];
    __shared__ unsigned short sAl[128][64];
    __shared__ unsigned short sBh[128][64];
    __shared__ unsigned short sBl[128][64];

    const int tid  = threadIdx.x;
    const int wave = tid >> 6;
    const int lane = tid & 63;
    const int quad = lane >> 4;
    const int l16  = lane & 15;
    const int wm   = wave >> 1;          // 0..3 -> 32-row strip
    const int wn   = wave & 1;           // 0..1 -> 64-col half

    const int j0 = blockIdx.x * 128;
    const int i0 = blockIdx.y * 128;

    const int sc  = tid & 7;
    const int r64 = tid >> 3;            // 0..63

    u16x8 preH[4], preL[4];

    #pragma unroll
    for (int p = 0; p < 4; ++p) {
        const int row256 = p * 64 + r64;
        const bool isA = row256 < 128;
        const int row = isA ? row256 : row256 - 128;
        const unsigned short* srcH = isA ? Ahi : Bhi;
        const unsigned short* srcL = isA ? Alo : Blo;
        const int grow = (isA ? i0 : j0) + row;
        const int cg = (sc ^ (row & 7)) * 8;
        const size_t go = (size_t)grow * 1024 + cg;
        preH[p] = *(const u16x8*)&srcH[go];
        preL[p] = *(const u16x8*)&srcL[go];
    }

    f32x4 acc[2][4] = {};

    for (int s = 0; s < 16; ++s) {
        __syncthreads();

        #pragma unroll
        for (int p = 0; p < 4; ++p) {
            const int row256 = p * 64 + r64;
            const bool isA = row256 < 128;
            const int row = isA ? row256 : row256 - 128;
            unsigned short (*dh)[64] = isA ? sAh : sBh;
            unsigned short (*dl)[64] = isA ? sAl : sBl;
            *(u16x8*)&dh[row][sc * 8] = preH[p];
            *(u16x8*)&dl[row][sc * 8] = preL[p];
        }
        __syncthreads();

        if (s + 1 < 16) {
            const int k0 = (s + 1) * 64;
            #pragma unroll
            for (int p = 0; p < 4; ++p) {
                const int row256 = p * 64 + r64;
                const bool isA = row256 < 128;
                const int row = isA ? row256 : row256 - 128;
                const unsigned short* srcH = isA ? Ahi : Bhi;
                const unsigned short* srcL = isA ? Alo : Blo;
                const int grow = (isA ? i0 : j0) + row;
                const int cg = (sc ^ (row & 7)) * 8;
                const size_t go = (size_t)grow * 1024 + k0 + cg;
                preH[p] = *(const u16x8*)&srcH[go];
                preL[p] = *(const u16x8*)&srcL[go];
            }
        }

        #pragma unroll
        for (int ks = 0; ks < 2; ++ks) {
            bf16x8 ah[2], al[2], bh[4], bl[4];
            #pragma unroll
            for (int mt = 0; mt < 2; ++mt) {
                const int row = wm * 32 + mt * 16 + l16;
                const int c = (((ks * 4 + quad) ^ (row & 7))) * 8;
                ah[mt] = *(const bf16x8*)&sAh[row][c];
                al[mt] = *(const bf16x8*)&sAl[row][c];
            }
            #pragma unroll
            for (int nt = 0; nt < 4; ++nt) {
                const int row = wn * 64 + nt * 16 + l16;
                const int c = (((ks * 4 + quad) ^ (row & 7))) * 8;
                bh[nt] = *(const bf16x8*)&sBh[row][c];
                bl[nt] = *(const bf16x8*)&sBl[row][c];
            }
            #pragma unroll
            for (int mt = 0; mt < 2; ++mt)
                #pragma unroll
                for (int nt = 0; nt < 4; ++nt) {
                    acc[mt][nt] = __builtin_amdgcn_mfma_f32_16x16x32_bf16(ah[mt], bh[nt], acc[mt][nt], 0, 0, 0);
                    acc[mt][nt] = __builtin_amdgcn_mfma_f32_16x16x32_bf16(ah[mt], bl[nt], acc[mt][nt], 0, 0, 0);
                    acc[mt][nt] = __builtin_amdgcn_mfma_f32_16x16x32_bf16(al[mt], bh[nt], acc[mt][nt], 0, 0, 0);
                }
        }
    }

    float bv[4];
    #pragma unroll
    for (int nt = 0; nt < 4; ++nt)
        bv[nt] = bias[j0 + wn * 64 + nt * 16 + l16];

    #pragma unroll
    for (int mt = 0; mt < 2; ++mt) {
        const int ibase = i0 + wm * 32 + mt * 16 + quad * 4;  // + r
        #pragma unroll
        for (int nt = 0; nt < 4; ++nt) {
            const int j = j0 + wn * 64 + nt * 16 + l16;
            #pragma unroll
            for (int r = 0; r < 4; ++r)
                Y[(size_t)(ibase + r) * 1024 + j] = (acc[mt][nt][r] + bv[nt]) * scale;
        }
    }
}

// ---------------------------------------------------------------------------
// bf16 MFMA flash attention v4 (R10).
// Change from R8: the P round-trip barrier (__syncthreads) is replaced by
// wave-level ordering. Safety argument: Ps[wave][..] is WAVE-PRIVATE (each
// wave reads only what it wrote); DS ops from one wave are processed in
// order by the LDS unit, so RAW at the LDS is guaranteed once the compiler
// cannot reorder the read before the writes — which the wave_barrier +
// "memory"-clobbered s_waitcnt asm enforces. (R3's race was exactly a
// compiler reorder; this pins it without a 256-thread sync.)
// The two STAGING barriers remain block-wide — Ks/Vt are block-shared.
// ---------------------------------------------------------------------------
__global__ __launch_bounds__(256) void flash_attn_mfma(
    const __hip_bfloat16* __restrict__ Qg,  // [BH][S][DEPTH], pre-scaled by 1/8
    const __hip_bfloat16* __restrict__ Kg,  // [BH][S][DEPTH]
    const __hip_bfloat16* __restrict__ Vg,  // [BH][DEPTH][S]
    unsigned short* __restrict__ OHi,       // [N_TOK][D_MODEL] bf16 hi
    unsigned short* __restrict__ OLo)       // [N_TOK][D_MODEL] bf16 lo
{
    __shared__ unsigned short Ks[64][72];
    __shared__ unsigned short Vt[64][72];
    __shared__ unsigned short Ps[4][16][68];

    const int tid  = threadIdx.x;
    const int wave = tid >> 6;
    const int lane = tid & 63;
    const int quad = lane >> 4;
    const int l16  = lane & 15;

    const int bh = blockIdx.x >> 5;
    const int q0 = (blockIdx.x & 31) * 64;

    const unsigned short* Qu = (const unsigned short*)Qg + (size_t)bh * SEQ * DEPTH;
    const unsigned short* Ku = (const unsigned short*)Kg + (size_t)bh * SEQ * DEPTH;
    const unsigned short* Vu = (const unsigned short*)Vg + (size_t)bh * DEPTH * SEQ;

    const int qrow = q0 + wave * 16 + l16;
    bf16x8 qf[2];
    qf[0] = *(const bf16x8*)&Qu[(size_t)qrow * DEPTH + quad * 8];
    qf[1] = *(const bf16x8*)&Qu[(size_t)qrow * DEPTH + 32 + quad * 8];

    bf16x8 ones;
    #pragma unroll
    for (int e = 0; e < 8; ++e) ones[e] = (short)0x3F80;  // bf16 1.0

    f32x4 o_acc[4] = {};
    f32x4 l_acc = {0.f, 0.f, 0.f, 0.f};

    const int srow = tid >> 3;          // 0..31
    const int sc8  = (tid & 7) * 8;
    u16x8 kpre[2], vpre[2];
    #pragma unroll
    for (int it = 0; it < 2; ++it) {
        const int row = it * 32 + srow;
        kpre[it] = *(const u16x8*)&Ku[(size_t)row * DEPTH + sc8];
        vpre[it] = *(const u16x8*)&Vu[(size_t)row * SEQ + sc8];
    }

    for (int t = 0; t < 32; ++t) {
        __syncthreads();  // prior tile's Ks/Vt reads complete (block-wide)

        #pragma unroll
        for (int it = 0; it < 2; ++it) {
            const int row = it * 32 + srow;
            *(u16x8*)&Ks[row][sc8] = kpre[it];
            *(u16x8*)&Vt[row][sc8] = vpre[it];
        }
        __syncthreads();

        if (t + 1 < 32) {
            const int k0 = (t + 1) * 64;
            #pragma unroll
            for (int it = 0; it < 2; ++it) {
                const int row = it * 32 + srow;
                kpre[it] = *(const u16x8*)&Ku[(size_t)(k0 + row) * DEPTH + sc8];
                vpre[it] = *(const u16x8*)&Vu[(size_t)row * SEQ + k0 + sc8];
            }
        }

        // ---- S = Q K^T (Q pre-scaled by 1/8) ----
        f32x4 s[4];
        #pragma unroll
        for (int nt = 0; nt < 4; ++nt) {
            s[nt] = f32x4{0.f, 0.f, 0.f, 0.f};
            bf16x8 kf0 = *(const bf16x8*)&Ks[nt * 16 + l16][quad * 8];
            s[nt] = __builtin_amdgcn_mfma_f32_16x16x32_bf16(qf[0], kf0, s[nt], 0, 0, 0);
            bf16x8 kf1 = *(const bf16x8*)&Ks[nt * 16 + l16][32 + quad * 8];
            s[nt] = __builtin_amdgcn_mfma_f32_16x16x32_bf16(qf[1], kf1, s[nt], 0, 0, 0);
        }

        // ---- p = exp(s) -> bf16 P strip (no max subtraction; see R7) ----
        #pragma unroll
        for (int nt = 0; nt < 4; ++nt)
            #pragma unroll
            for (int r = 0; r < 4; ++r)
                Ps[wave][quad * 4 + r][nt * 16 + l16] = f2b(__expf(s[nt][r]));

        // R10: wave-private P round-trip — wave-level ordering only.
        __builtin_amdgcn_wave_barrier();
        __asm__ volatile("s_waitcnt lgkmcnt(0)" ::: "memory");
        __builtin_amdgcn_wave_barrier();

        // ---- reread P as A-fragments (2 x b64 per frag; pitch-68 rows) ----
        bf16x8 pf[2];
        {
            u16x4 a0 = *(const u16x4*)&Ps[wave][l16][quad * 8];
            u16x4 a1 = *(const u16x4*)&Ps[wave][l16][quad * 8 + 4];
            u16x4 b0 = *(const u16x4*)&Ps[wave][l16][32 + quad * 8];
            u16x4 b1 = *(const u16x4*)&Ps[wave][l16][32 + quad * 8 + 4];
            #pragma unroll
            for (int e = 0; e < 4; ++e) {
                pf[0][e] = (short)a0[e]; pf[0][4 + e] = (short)a1[e];
                pf[1][e] = (short)b0[e]; pf[1][4 + e] = (short)b1[e];
            }
        }

        // ---- O += P V ; row sums += P @ ones ----
        #pragma unroll
        for (int nt = 0; nt < 4; ++nt) {
            bf16x8 vf0 = *(const bf16x8*)&Vt[nt * 16 + l16][quad * 8];
            o_acc[nt] = __builtin_amdgcn_mfma_f32_16x16x32_bf16(pf[0], vf0, o_acc[nt], 0, 0, 0);
            bf16x8 vf1 = *(const bf16x8*)&Vt[nt * 16 + l16][32 + quad * 8];
            o_acc[nt] = __builtin_amdgcn_mfma_f32_16x16x32_bf16(pf[1], vf1, o_acc[nt], 0, 0, 0);
        }
        l_acc = __builtin_amdgcn_mfma_f32_16x16x32_bf16(pf[0], ones, l_acc, 0, 0, 0);
        l_acc = __builtin_amdgcn_mfma_f32_16x16x32_bf16(pf[1], ones, l_acc, 0, 0, 0);
    }

    // ---- epilogue: normalize, split-store hi/lo ----
    const int b = bh / NUM_HEADS;
    const int h = bh % NUM_HEADS;
    #pragma unroll
    for (int r = 0; r < 4; ++r) {
        const float inv = 1.f / l_acc[r];
        const int row = q0 + wave * 16 + quad * 4 + r;
        #pragma unroll
        for (int nt = 0; nt < 4; ++nt) {
            const float o = o_acc[nt][r] * inv;
            const size_t idx = ((size_t)(b * SEQ + row)) * D_MODEL + h * DEPTH + nt * 16 + l16;
            const unsigned short hbits = f2b(o);
            OHi[idx] = hbits;
            OLo[idx] = f2b(o - b2f(hbits));
        }
    }
}

// ---------------------------------------------------------------------------
extern "C" void kernel_launch(void* const* d_in, const int* in_sizes, int n_in,
                              void* d_out, int out_size, void* d_ws, size_t ws_size,
                              hipStream_t stream) {
    const float* q  = (const float*)d_in[0];
    const float* k  = (const float*)d_in[1];
    const float* v  = (const float*)d_in[2];
    const float* wq = (const float*)d_in[3];
    const float* bq = (const float*)d_in[4];
    const float* wk = (const float*)d_in[5];
    const float* bk = (const float*)d_in[6];
    const float* wv = (const float*)d_in[7];
    const float* bv = (const float*)d_in[8];
    const float* wo = (const float*)d_in[9];
    const float* bo = (const float*)d_in[10];
    float* out = (float*)d_out;

    // Workspace (50 MB):
    //  [0,  8) Af16 (fp16 input, recycled q->k->v), then AoHi (bf16) after attn
    //  [8, 16) AoLo
    //  [16,18) WqF fp16  [18,20) WkF  [20,22) WvF  [22,24) WoH  [24,26) WoL
    //  [26,34) Qh  [34,42) Kh  [42,50) Vh
    char* ws = (char*)d_ws;
    const size_t MB = 1024 * 1024;
    unsigned short* Af16 = (unsigned short*)(ws);
    unsigned short* AoHi = (unsigned short*)(ws);          // after attn
    unsigned short* AoLo = (unsigned short*)(ws + 8 * MB);
    unsigned short* WqF  = (unsigned short*)(ws + 16 * MB);
    unsigned short* WkF  = (unsigned short*)(ws + 18 * MB);
    unsigned short* WvF  = (unsigned short*)(ws + 20 * MB);
    unsigned short* WoH  = (unsigned short*)(ws + 22 * MB);
    unsigned short* WoL  = (unsigned short*)(ws + 24 * MB);
    __hip_bfloat16* Qh   = (__hip_bfloat16*)(ws + 26 * MB);
    __hip_bfloat16* Kh   = (__hip_bfloat16*)(ws + 34 * MB);
    __hip_bfloat16* Vh   = (__hip_bfloat16*)(ws + 42 * MB);

    const int nW8 = D_MODEL * D_MODEL / 8;   // 131072
    const int nA8 = N_TOK * D_MODEL / 8;     // 524288
    dim3 sb(256);

    prep_weights<<<dim3(nW8 / 256, 4), sb, 0, stream>>>(
        wq, wk, wv, wo, WqF, WkF, WvF, WoH, WoL, nW8);

    dim3 fblk(256);
    dim3 fgrid(D_MODEL / 64, N_TOK / 64);    // 16 x 64 = 1024 blocks

    // Q projection (scale folds 1/sqrt(64) into Q)
    split_f16<<<dim3(nA8 / 256), sb, 0, stream>>>(q, Af16, nA8);
    gemm_f16<<<fgrid, fblk, 0, stream>>>(Af16, WqF, bq, Qh, 0.125f, 1);
    // K projection
    split_f16<<<dim3(nA8 / 256), sb, 0, stream>>>(k, Af16, nA8);
    gemm_f16<<<fgrid, fblk, 0, stream>>>(Af16, WkF, bk, Kh, 1.0f, 1);
    // V projection (transposed head layout)
    split_f16<<<dim3(nA8 / 256), sb, 0, stream>>>(v, Af16, nA8);
    gemm_f16<<<fgrid, fblk, 0, stream>>>(Af16, WvF, bv, Vh, 1.0f, 2);

    // attention -> Ao (pre-split hi/lo; Af16 is dead by now)
    dim3 ablk(256);
    dim3 agrid(BATCH * NUM_HEADS * (SEQ / 64));  // 1024 blocks
    flash_attn_mfma<<<agrid, ablk, 0, stream>>>(Qh, Kh, Vh, AoHi, AoLo);

    // output projection (bf16x3 — error lands directly on d_out)
    dim3 oblk(512);
    dim3 ogrid(D_MODEL / 128, N_TOK / 128);  // 8 x 32 = 256 blocks
    gemm_bf16x3<<<ogrid, oblk, 0, stream>>>(AoHi, AoLo, WoH, WoL, bo, out, 1.0f);
}